// Round 19
// baseline (61.919 us; speedup 1.0000x reference)
//
#include <hip/hip_runtime.h>
#include <cstddef>
#include <cstdint>

#define BETA 0.05f

typedef unsigned short u16;
typedef unsigned int u32;
typedef __attribute__((ext_vector_type(8))) short bf16x8;
typedef __attribute__((ext_vector_type(16))) float f32x16;
typedef __attribute__((ext_vector_type(4))) u32 u32x4;

constexpr int NQ = 8192;
constexpr int NK = 8192;
constexpr int DH = 128;
constexpr int SPLITS = 16;
constexpr int CHUNK = NK / SPLITS;   // 512
constexpr int KVB = 32;
constexpr int STEPS = CHUNK / KVB;   // 16
constexpr int KSTEP = 8192;          // 8 chunks x 1024 B per step (K)
constexpr int VSTEP = 8192;          // 8 chunks x 1024 B per step (V)
constexpr int LDS_BYTES = 2 * KSTEP + 2 * VSTEP + 2048;  // 34816 -> 3 blocks/CU (reg-capped)

// Fragment-major global layouts (chunk = 64 lanes x 16B = 1024B, one wave-load):
//  Kf chunk (tile32, sl=0..7): lane (hi,rr) holds K dims [sl*16+hi*8,+8) of kv row tile*32+rr
//  Vf chunk (b16, dt=0..3):    lane (hi,r31) holds V[kv=b16*16+hi*8..+8][d=dt*32+r31]
//  B2f[tile32][hi*16+r] f32 = b2 of kv row tile*32 + (r&3)+8*(r>>2)+4*hi  (C-layout match)

__device__ __forceinline__ u16 f2bf(float x) {
  union { float f; u32 u; } v; v.f = x;
  u32 r = (v.u + 0x7fffu + ((v.u >> 16) & 1u)) >> 16;
  return (u16)r;
}
__device__ __forceinline__ float fexp2(float x) {
#if __has_builtin(__builtin_amdgcn_exp2f)
  return __builtin_amdgcn_exp2f(x);
#else
  return exp2f(x);
#endif
}
// async global->LDS, 16B/lane; dst wave-uniform base (HW adds lane*16), src per-lane
__device__ __forceinline__ void gload_lds16(const void* gsrc, void* ldst) {
  __builtin_amdgcn_global_load_lds(
      (const __attribute__((address_space(1))) u32*)gsrc,
      (__attribute__((address_space(3))) u32*)ldst, 16, 0, 0);
}

// ---------- fused prep: Q rows | K fragment-major + b2 | V fragment-major ----------
__global__ void prep_all(const float* __restrict__ Q, const float* __restrict__ ldq,
                         const float* __restrict__ K, const float* __restrict__ ldk,
                         const float* __restrict__ h, const float* __restrict__ V,
                         u16* __restrict__ Qa, u16* __restrict__ Kf,
                         float* __restrict__ B2f, float* __restrict__ arow,
                         u16* __restrict__ Vf) {
  __shared__ float tile[64][65];
  const int bi = blockIdx.x;
  const int lane = threadIdx.x & 63;
  if (bi < NQ / 4) {
    const int row = bi * 4 + (threadIdx.x >> 6);
    const float2 q2 = *(const float2*)(Q + (size_t)row * DH + lane * 2);
    float sq = q2.x * q2.x + q2.y * q2.y;
#pragma unroll
    for (int off = 32; off > 0; off >>= 1) sq += __shfl_xor(sq, off);
    const float SC = 2.0f * BETA * 1.4426950408889634f;  // fold 2*beta*log2e
    ushort2 o; o.x = f2bf(SC * q2.x); o.y = f2bf(SC * q2.y);
    *(ushort2*)(Qa + (size_t)row * DH + lane * 2) = o;
    if (lane == 0) arow[row] = -BETA * sq - ldq[row] + logf(h[row]);
  } else if (bi < NQ / 2) {
    const int row = (bi - NQ / 4) * 4 + (threadIdx.x >> 6);
    const float2 k2 = *(const float2*)(K + (size_t)row * DH + lane * 2);
    float sq = k2.x * k2.x + k2.y * k2.y;
#pragma unroll
    for (int off = 32; off > 0; off >>= 1) sq += __shfl_xor(sq, off);
    ushort2 o; o.x = f2bf(k2.x); o.y = f2bf(k2.y);
    char* dst = (char*)Kf + ((size_t)(row >> 5) * 8 + (lane >> 3)) * 1024
              + ((((lane >> 2) & 1) * 32) + (row & 31)) * 16 + (lane & 3) * 4;
    *(ushort2*)dst = o;
    if (lane == 0) {
      const float b2 = (-BETA * sq - ldk[row] - logf(h[row])) * 1.4426950408889634f;
      const int w = row & 31;
      B2f[(size_t)(row >> 5) * 32 + ((w >> 2) & 1) * 16 + (w & 3) + 4 * (w >> 3)] = b2;
    }
  } else {
    // V transpose blocks: vb = bi - NQ/2 in [0, 256); j0 = (vb>>1)*64, d0 = (vb&1)*64
    const int vb = bi - NQ / 2;
    const int j0 = (vb >> 1) * 64;
    const int d0 = (vb & 1) * 64;
    const int t = threadIdx.x;        // 256
    const int r = t >> 4;
    const int c = (t & 15) * 4;
#pragma unroll
    for (int rr = r; rr < 64; rr += 16) {
      const float4 v = *(const float4*)(V + (size_t)(j0 + rr) * DH + d0 + c);
      tile[rr][c + 0] = v.x; tile[rr][c + 1] = v.y;
      tile[rr][c + 2] = v.z; tile[rr][c + 3] = v.w;
    }
    __syncthreads();
    const int kv8i = t & 7;
    const int dl0 = t >> 3;           // 0..31
#pragma unroll
    for (int dd = dl0; dd < 64; dd += 32) {
      const int dg = d0 + dd;
      const int b16g = (j0 >> 4) + (kv8i >> 1);
      const int hi = kv8i & 1;
      union { u32x4 q; u16 s[8]; } pk;
#pragma unroll
      for (int m = 0; m < 8; ++m) pk.s[m] = f2bf(tile[kv8i * 8 + m][dd]);
      *(u32x4*)((char*)Vf + ((size_t)(b16g * 4 + (dg >> 5)) * 1024)
                + ((hi * 32) + (dg & 31)) * 16) = pk.q;
    }
  }
}

// softmax + PV for one 32-kv tile; dual-chain s = sA + sB; V reads fused into PV
__device__ __forceinline__ void smpv2(const f32x16& sA, const f32x16& sB,
                                      const char* vbh,
                                      f32x16 acc[4], float& lsum, int hi) {
  float p[16];
#pragma unroll
  for (int r = 0; r < 16; ++r) p[r] = fexp2(sA[r] + sB[r]);
  {
    float t0 = (p[0] + p[1]) + (p[2] + p[3]);
    float t1 = (p[4] + p[5]) + (p[6] + p[7]);
    float t2 = (p[8] + p[9]) + (p[10] + p[11]);
    float t3 = (p[12] + p[13]) + (p[14] + p[15]);
    lsum += (t0 + t1) + (t2 + t3);
  }
  u32 pk0, pk1, pk2, pk3, pk4, pk5, pk6, pk7;
  asm("v_cvt_pk_bf16_f32 %0, %1, %2" : "=v"(pk0) : "v"(p[0]),  "v"(p[1]));
  asm("v_cvt_pk_bf16_f32 %0, %1, %2" : "=v"(pk1) : "v"(p[2]),  "v"(p[3]));
  asm("v_cvt_pk_bf16_f32 %0, %1, %2" : "=v"(pk2) : "v"(p[4]),  "v"(p[5]));
  asm("v_cvt_pk_bf16_f32 %0, %1, %2" : "=v"(pk3) : "v"(p[6]),  "v"(p[7]));
  asm("v_cvt_pk_bf16_f32 %0, %1, %2" : "=v"(pk4) : "v"(p[8]),  "v"(p[9]));
  asm("v_cvt_pk_bf16_f32 %0, %1, %2" : "=v"(pk5) : "v"(p[10]), "v"(p[11]));
  asm("v_cvt_pk_bf16_f32 %0, %1, %2" : "=v"(pk6) : "v"(p[12]), "v"(p[13]));
  asm("v_cvt_pk_bf16_f32 %0, %1, %2" : "=v"(pk7) : "v"(p[14]), "v"(p[15]));
  const bool hb = (hi != 0);
#pragma unroll
  for (int ksl = 0; ksl < 2; ++ksl) {
    const u32 a0 = ksl ? pk4 : pk0, a1 = ksl ? pk5 : pk1;
    const u32 b0 = ksl ? pk6 : pk2, b1 = ksl ? pk7 : pk3;
    const u32 own0 = hb ? b0 : a0, own1 = hb ? b1 : a1;
    const u32 snd0 = hb ? a0 : b0, snd1 = hb ? a1 : b1;
    const u32 rcv0 = (u32)__shfl_xor((int)snd0, 32);
    const u32 rcv1 = (u32)__shfl_xor((int)snd1, 32);
    union { u32x4 u; bf16x8 b; } pa;
    pa.u[0] = hb ? rcv0 : own0;
    pa.u[1] = hb ? rcv1 : own1;
    pa.u[2] = hb ? own0 : rcv0;
    pa.u[3] = hb ? own1 : rcv1;
#pragma unroll
    for (int dt = 0; dt < 4; ++dt) {
      const bf16x8 vf = *(const bf16x8*)(vbh + (ksl * 4 + dt) * 1024);
      acc[dt] = __builtin_amdgcn_mfma_f32_32x32x16_bf16(pa.b, vf, acc[dt], 0, 0, 0);
    }
  }
}

// ---------- main: 4-wave blocks, 3 blocks/CU (12 waves, phase-staggered) ----------
__global__ __launch_bounds__(256, 3) void attn_main(
    const u16* __restrict__ Qa, const u16* __restrict__ Kf,
    const u16* __restrict__ Vf, const float* __restrict__ B2f,
    u16* __restrict__ Opart, float* __restrict__ Lpart) {
  extern __shared__ __align__(16) char lds[];    // 34816 B dynamic
  char* ldsK = lds;                              // [2][8192]
  char* ldsV = lds + 2 * KSTEP;                  // [2][8192]
  char* ldsB = lds + 2 * KSTEP + 2 * VSTEP;      // [2048]

  const int tid = threadIdx.x;
  const int wid = tid >> 6;       // 0..3
  const int lane = tid & 63;
  const int hi = lane >> 5;
  const int ln31 = lane & 31;
  const int bi = blockIdx.x;
  const int ks = bi & 15;         // split id (ks&7 -> XCD chunk locality)
  const int qg = bi >> 4;         // 0..63
  const int kvbase = ks * CHUNK;
  const int qrow0 = qg * 128 + wid * 32;

  // Q fragments (B-operand): col q = ln31, dims sl*16 + hi*8 + j
  bf16x8 qf[8];
#pragma unroll
  for (int sl = 0; sl < 8; ++sl)
    qf[sl] = *(const bf16x8*)((const char*)Qa + (size_t)(qrow0 + ln31) * 256 + sl * 32 + hi * 16);

  f32x16 acc[4];
#pragma unroll
  for (int dt = 0; dt < 4; ++dt)
#pragma unroll
    for (int r = 0; r < 16; ++r) acc[dt][r] = 0.0f;
  float lsum = 0.0f;

  const char* KfG = (const char*)Kf + ((size_t)(kvbase >> 5) * 8) * 1024 + lane * 16;
  const char* VfG = (const char*)Vf + ((size_t)(kvbase >> 4) * 4) * 1024 + lane * 16;

  // stage: wave w moves K chunks {2w,2w+1} + V chunks {2w,2w+1} of step into buf
  auto STAGE = [&](int buf, int step) {
    const char* ksrc = KfG + (size_t)step * KSTEP + wid * 2048;
    const char* vsrc = VfG + (size_t)step * VSTEP + wid * 2048;
    char* kdst = ldsK + buf * KSTEP + wid * 2048;
    char* vdst = ldsV + buf * VSTEP + wid * 2048;
    gload_lds16(ksrc, kdst);
    gload_lds16(ksrc + 1024, kdst + 1024);
    gload_lds16(vsrc, vdst);
    gload_lds16(vsrc + 1024, vdst + 1024);
  };

  // prologue: B2 chunk (2KB over waves 0,1) + step-0 tiles
  if (wid < 2)
    gload_lds16((const char*)B2f + (size_t)(kvbase >> 5) * 128 + wid * 1024 + lane * 16,
                ldsB + wid * 1024);
  STAGE(0, 0);
  __syncthreads();

  for (int t = 0; t < STEPS; ++t) {
    const int cur = t & 1;
    if (t < STEPS - 1) STAGE(cur ^ 1, t + 1);   // drains at end-of-step barrier

    const char* kb = ldsK + cur * KSTEP + lane * 16;
    const char* vb = ldsV + cur * VSTEP + lane * 16;

    // ---- QK: dual chains (even->A with b2-init, odd->B), fused reads ----
    f32x16 sA = *(const f32x16*)(ldsB + t * 128 + hi * 64);
    f32x16 sB;
#pragma unroll
    for (int r = 0; r < 16; ++r) sB[r] = 0.0f;
#pragma unroll
    for (int sl = 0; sl < 8; ++sl) {
      const bf16x8 kf = *(const bf16x8*)(kb + sl * 1024);
      if (sl & 1)
        sB = __builtin_amdgcn_mfma_f32_32x32x16_bf16(kf, qf[sl], sB, 0, 0, 0);
      else
        sA = __builtin_amdgcn_mfma_f32_32x32x16_bf16(kf, qf[sl], sA, 0, 0, 0);
    }
    smpv2(sA, sB, vb, acc, lsum, hi);

    __syncthreads();   // staged buf complete + all reads of cur done
  }

  // ---- epilogue: partner half of L, write bf16 partials ----
  lsum += __shfl_xor(lsum, 32);
  u16* op = Opart + ((size_t)ks * NQ + qrow0) * DH;
#pragma unroll
  for (int dt = 0; dt < 4; ++dt)
#pragma unroll
    for (int r = 0; r < 16; ++r) {
      const int q = (r & 3) + 8 * (r >> 2) + 4 * hi;
      op[(size_t)q * DH + dt * 32 + ln31] = f2bf(acc[dt][r]);
    }
  if (hi == 0) Lpart[(size_t)ks * NQ + qrow0 + ln31] = lsum;
}

// ---------- combine: plain sums over splits ----------
__global__ void combine(const u16* __restrict__ Opart, const float* __restrict__ Lpart,
                        const float* __restrict__ arow, float* __restrict__ out,
                        float* __restrict__ lse) {
  const int idx = blockIdx.x * 256 + threadIdx.x;
  const int row = idx >> 5;
  const int d4 = (idx & 31) * 4;
  float o0 = 0.f, o1 = 0.f, o2 = 0.f, o3 = 0.f;
  float L = 0.f;
#pragma unroll
  for (int s = 0; s < SPLITS; ++s) {
    const ushort4 v = *(const ushort4*)(Opart + ((size_t)s * NQ + row) * DH + d4);
    union { u32 u; float f; } c0, c1, c2, c3;
    c0.u = ((u32)v.x) << 16; c1.u = ((u32)v.y) << 16;
    c2.u = ((u32)v.z) << 16; c3.u = ((u32)v.w) << 16;
    o0 += c0.f; o1 += c1.f; o2 += c2.f; o3 += c3.f;
    L += Lpart[(size_t)s * NQ + row];
  }
  const float inv = 1.0f / L;
  *(float4*)(out + (size_t)row * DH + d4) =
      make_float4(o0 * inv, o1 * inv, o2 * inv, o3 * inv);
  if ((idx & 31) == 0) lse[row] = logf(L) + arow[row];
}

extern "C" void kernel_launch(void* const* d_in, const int* in_sizes, int n_in,
                              void* d_out, int out_size, void* d_ws, size_t ws_size,
                              hipStream_t stream) {
  const float* Q = (const float*)d_in[0];
  const float* K = (const float*)d_in[1];
  const float* V = (const float*)d_in[2];
  const float* h = (const float*)d_in[3];
  const float* ldq = (const float*)d_in[4];
  const float* ldk = (const float*)d_in[5];

  char* ws = (char*)d_ws;
  u16* Qa    = (u16*)(ws + 0);                       // 8192*128*2 = 2097152
  u16* Kf    = (u16*)(ws + 2097152);                 // 256*8*1024 = 2097152
  u16* Vf    = (u16*)(ws + 4194304);                 // 512*4*1024 = 2097152
  float* B2f   = (float*)(ws + 6291456);             // 8192*4 = 32768
  float* arow  = (float*)(ws + 6324224);             // 32768
  u16* Opart = (u16*)(ws + 6356992);                 // 16*8192*128*2 = 33554432
  float* Lpart = (float*)(ws + 39911424);            // 16*8192*4 = 524288 (end 40435712)

  float* out = (float*)d_out;
  float* lse = out + (size_t)NQ * DH;

  prep_all<<<NQ / 2 + 256, 256, 0, stream>>>(Q, ldq, K, ldk, h, V, Qa, Kf, B2f, arow, Vf);
  attn_main<<<(NQ / 128) * SPLITS, 256, LDS_BYTES, stream>>>(Qa, Kf, Vf, B2f, Opart, Lpart);
  combine<<<NQ * 32 / 256, 256, 0, stream>>>(Opart, Lpart, arow, out, lse);
}

// Round 20
// 55.079 us; speedup vs baseline: 1.1242x; 1.1242x over previous
//
#include <hip/hip_runtime.h>
#include <cstddef>
#include <cstdint>

#define BETA 0.05f

typedef unsigned short u16;
typedef unsigned int u32;
typedef __attribute__((ext_vector_type(8))) short bf16x8;
typedef __attribute__((ext_vector_type(16))) float f32x16;
typedef __attribute__((ext_vector_type(4))) u32 u32x4;

constexpr int NQ = 8192;
constexpr int NK = 8192;
constexpr int DH = 128;
constexpr int SPLITS = 8;
constexpr int CHUNK = NK / SPLITS;   // 1024
constexpr int KVB = 64;
constexpr int STEPS = CHUNK / KVB;   // 16
constexpr int KSTEP = 16384;         // 16 chunks x 1024 B per step (K)
constexpr int VSTEP = 16384;         // 16 chunks x 1024 B per step (V)
constexpr int LDS_BYTES = 2 * KSTEP + 2 * VSTEP + 4096;  // 69632

// Fragment-major global layouts (chunk = 64 lanes x 16B = 1024B, one wave-load):
//  Kf chunk (tile32, sl=0..7): lane (hi,rr) holds K dims [sl*16+hi*8,+8) of kv row tile*32+rr
//  Vf chunk (b16, dt=0..3):    lane (hi,r31) holds V[kv=b16*16+hi*8..+8][d=dt*32+r31]
//  B2f[tile32][hi*16+r] f32 = b2 of kv row tile*32 + (r&3)+8*(r>>2)+4*hi  (C-layout match)

__device__ __forceinline__ u16 f2bf(float x) {
  union { float f; u32 u; } v; v.f = x;
  u32 r = (v.u + 0x7fffu + ((v.u >> 16) & 1u)) >> 16;
  return (u16)r;
}
__device__ __forceinline__ float fexp2(float x) {
#if __has_builtin(__builtin_amdgcn_exp2f)
  return __builtin_amdgcn_exp2f(x);
#else
  return exp2f(x);
#endif
}
// async global->LDS, 16B/lane; dst wave-uniform base (HW adds lane*16), src per-lane
__device__ __forceinline__ void gload_lds16(const void* gsrc, void* ldst) {
  __builtin_amdgcn_global_load_lds(
      (const __attribute__((address_space(1))) u32*)gsrc,
      (__attribute__((address_space(3))) u32*)ldst, 16, 0, 0);
}

// ---------- fused prep: Q rows | K fragment-major + b2 | V fragment-major ----------
__global__ void prep_all(const float* __restrict__ Q, const float* __restrict__ ldq,
                         const float* __restrict__ K, const float* __restrict__ ldk,
                         const float* __restrict__ h, const float* __restrict__ V,
                         u16* __restrict__ Qa, u16* __restrict__ Kf,
                         float* __restrict__ B2f, float* __restrict__ arow,
                         u16* __restrict__ Vf) {
  __shared__ float tile[64][65];
  const int bi = blockIdx.x;
  const int lane = threadIdx.x & 63;
  if (bi < NQ / 4) {
    const int row = bi * 4 + (threadIdx.x >> 6);
    const float2 q2 = *(const float2*)(Q + (size_t)row * DH + lane * 2);
    float sq = q2.x * q2.x + q2.y * q2.y;
#pragma unroll
    for (int off = 32; off > 0; off >>= 1) sq += __shfl_xor(sq, off);
    const float SC = 2.0f * BETA * 1.4426950408889634f;  // fold 2*beta*log2e
    ushort2 o; o.x = f2bf(SC * q2.x); o.y = f2bf(SC * q2.y);
    *(ushort2*)(Qa + (size_t)row * DH + lane * 2) = o;
    if (lane == 0) arow[row] = -BETA * sq - ldq[row] + logf(h[row]);
  } else if (bi < NQ / 2) {
    const int row = (bi - NQ / 4) * 4 + (threadIdx.x >> 6);
    const float2 k2 = *(const float2*)(K + (size_t)row * DH + lane * 2);
    float sq = k2.x * k2.x + k2.y * k2.y;
#pragma unroll
    for (int off = 32; off > 0; off >>= 1) sq += __shfl_xor(sq, off);
    ushort2 o; o.x = f2bf(k2.x); o.y = f2bf(k2.y);
    char* dst = (char*)Kf + ((size_t)(row >> 5) * 8 + (lane >> 3)) * 1024
              + ((((lane >> 2) & 1) * 32) + (row & 31)) * 16 + (lane & 3) * 4;
    *(ushort2*)dst = o;
    if (lane == 0) {
      const float b2 = (-BETA * sq - ldk[row] - logf(h[row])) * 1.4426950408889634f;
      const int w = row & 31;
      B2f[(size_t)(row >> 5) * 32 + ((w >> 2) & 1) * 16 + (w & 3) + 4 * (w >> 3)] = b2;
    }
  } else {
    // V transpose blocks: vb = bi - NQ/2 in [0, 256); j0 = (vb>>1)*64, d0 = (vb&1)*64
    const int vb = bi - NQ / 2;
    const int j0 = (vb >> 1) * 64;
    const int d0 = (vb & 1) * 64;
    const int t = threadIdx.x;        // 256
    const int r = t >> 4;
    const int c = (t & 15) * 4;
#pragma unroll
    for (int rr = r; rr < 64; rr += 16) {
      const float4 v = *(const float4*)(V + (size_t)(j0 + rr) * DH + d0 + c);
      tile[rr][c + 0] = v.x; tile[rr][c + 1] = v.y;
      tile[rr][c + 2] = v.z; tile[rr][c + 3] = v.w;
    }
    __syncthreads();
    const int kv8i = t & 7;
    const int dl0 = t >> 3;           // 0..31
#pragma unroll
    for (int dd = dl0; dd < 64; dd += 32) {
      const int dg = d0 + dd;
      const int b16g = (j0 >> 4) + (kv8i >> 1);
      const int hi = kv8i & 1;
      union { u32x4 q; u16 s[8]; } pk;
#pragma unroll
      for (int m = 0; m < 8; ++m) pk.s[m] = f2bf(tile[kv8i * 8 + m][dd]);
      *(u32x4*)((char*)Vf + ((size_t)(b16g * 4 + (dg >> 5)) * 1024)
                + ((hi * 32) + (dg & 31)) * 16) = pk.q;
    }
  }
}

// softmax + PV for one 32-kv half; dual-chain s = sA + sB; V reads fused into PV
__device__ __forceinline__ void smpv2(const f32x16& sA, const f32x16& sB,
                                      const char* vbh,
                                      f32x16 acc[4], float& lsum, int hi) {
  float p[16];
#pragma unroll
  for (int r = 0; r < 16; ++r) p[r] = fexp2(sA[r] + sB[r]);
  {
    float t0 = (p[0] + p[1]) + (p[2] + p[3]);
    float t1 = (p[4] + p[5]) + (p[6] + p[7]);
    float t2 = (p[8] + p[9]) + (p[10] + p[11]);
    float t3 = (p[12] + p[13]) + (p[14] + p[15]);
    lsum += (t0 + t1) + (t2 + t3);
  }
  u32 pk0, pk1, pk2, pk3, pk4, pk5, pk6, pk7;
  asm("v_cvt_pk_bf16_f32 %0, %1, %2" : "=v"(pk0) : "v"(p[0]),  "v"(p[1]));
  asm("v_cvt_pk_bf16_f32 %0, %1, %2" : "=v"(pk1) : "v"(p[2]),  "v"(p[3]));
  asm("v_cvt_pk_bf16_f32 %0, %1, %2" : "=v"(pk2) : "v"(p[4]),  "v"(p[5]));
  asm("v_cvt_pk_bf16_f32 %0, %1, %2" : "=v"(pk3) : "v"(p[6]),  "v"(p[7]));
  asm("v_cvt_pk_bf16_f32 %0, %1, %2" : "=v"(pk4) : "v"(p[8]),  "v"(p[9]));
  asm("v_cvt_pk_bf16_f32 %0, %1, %2" : "=v"(pk5) : "v"(p[10]), "v"(p[11]));
  asm("v_cvt_pk_bf16_f32 %0, %1, %2" : "=v"(pk6) : "v"(p[12]), "v"(p[13]));
  asm("v_cvt_pk_bf16_f32 %0, %1, %2" : "=v"(pk7) : "v"(p[14]), "v"(p[15]));
  const bool hb = (hi != 0);
#pragma unroll
  for (int ksl = 0; ksl < 2; ++ksl) {
    const u32 a0 = ksl ? pk4 : pk0, a1 = ksl ? pk5 : pk1;
    const u32 b0 = ksl ? pk6 : pk2, b1 = ksl ? pk7 : pk3;
    const u32 own0 = hb ? b0 : a0, own1 = hb ? b1 : a1;
    const u32 snd0 = hb ? a0 : b0, snd1 = hb ? a1 : b1;
    const u32 rcv0 = (u32)__shfl_xor((int)snd0, 32);
    const u32 rcv1 = (u32)__shfl_xor((int)snd1, 32);
    union { u32x4 u; bf16x8 b; } pa;
    pa.u[0] = hb ? rcv0 : own0;
    pa.u[1] = hb ? rcv1 : own1;
    pa.u[2] = hb ? own0 : rcv0;
    pa.u[3] = hb ? own1 : rcv1;
#pragma unroll
    for (int dt = 0; dt < 4; ++dt) {
      const bf16x8 vf = *(const bf16x8*)(vbh + (ksl * 4 + dt) * 1024);
      acc[dt] = __builtin_amdgcn_mfma_f32_32x32x16_bf16(pa.b, vf, acc[dt], 0, 0, 0);
    }
  }
}

// ---------- main: fragment-major + LDS distribution (r18 config, best) ----------
__global__ __launch_bounds__(512) void attn_main(
    const u16* __restrict__ Qa, const u16* __restrict__ Kf,
    const u16* __restrict__ Vf, const float* __restrict__ B2f,
    u16* __restrict__ Opart, float* __restrict__ Lpart) {
  extern __shared__ __align__(16) char lds[];    // 69632 B dynamic
  char* ldsK = lds;                              // [2][16384]
  char* ldsV = lds + 2 * KSTEP;                  // [2][16384]
  char* ldsB = lds + 2 * KSTEP + 2 * VSTEP;      // [4096]

  const int tid = threadIdx.x;
  const int wid = tid >> 6;
  const int lane = tid & 63;
  const int hi = lane >> 5;
  const int ln31 = lane & 31;
  const int bi = blockIdx.x;
  const int ks = bi & 7;          // split id -> XCD (L2 chunk locality)
  const int qg = bi >> 3;
  const int kvbase = ks * CHUNK;
  const int qrow0 = qg * 256 + wid * 32;

  // Q fragments (B-operand): col q = ln31, dims sl*16 + hi*8 + j
  bf16x8 qf[8];
#pragma unroll
  for (int sl = 0; sl < 8; ++sl)
    qf[sl] = *(const bf16x8*)((const char*)Qa + (size_t)(qrow0 + ln31) * 256 + sl * 32 + hi * 16);

  f32x16 acc[4];
#pragma unroll
  for (int dt = 0; dt < 4; ++dt)
#pragma unroll
    for (int r = 0; r < 16; ++r) acc[dt][r] = 0.0f;
  float lsum = 0.0f;

  const char* KfG = (const char*)Kf + ((size_t)(kvbase >> 5) * 8) * 1024 + lane * 16;
  const char* VfG = (const char*)Vf + ((size_t)(kvbase >> 4) * 4) * 1024 + lane * 16;

  // stage: wave w moves K chunks {2w,2w+1} + V chunks {2w,2w+1} of step into buf
  auto STAGE = [&](int buf, int step) {
    const char* ksrc = KfG + (size_t)step * KSTEP + wid * 2048;
    const char* vsrc = VfG + (size_t)step * VSTEP + wid * 2048;
    char* kdst = ldsK + buf * KSTEP + wid * 2048;
    char* vdst = ldsV + buf * VSTEP + wid * 2048;
    gload_lds16(ksrc, kdst);
    gload_lds16(ksrc + 1024, kdst + 1024);
    gload_lds16(vsrc, vdst);
    gload_lds16(vsrc + 1024, vdst + 1024);
  };

  // one full step on compile-time buffer index `cur`
  auto BODY = [&](int cur, int t) {
    if (t < STEPS - 1) STAGE(cur ^ 1, t + 1);   // drains at end-of-step barrier

    const char* kb = ldsK + cur * KSTEP + lane * 16;
    const char* vb = ldsV + cur * VSTEP + lane * 16;

    // ---- QK half 0: dual chains (even->A with b2-init, odd->B), fused reads ----
    f32x16 sA0 = *(const f32x16*)(ldsB + t * 256 + hi * 64);
    f32x16 sB0;
#pragma unroll
    for (int r = 0; r < 16; ++r) sB0[r] = 0.0f;
#pragma unroll
    for (int sl = 0; sl < 8; ++sl) {
      const bf16x8 kf = *(const bf16x8*)(kb + sl * 1024);
      if (sl & 1)
        sB0 = __builtin_amdgcn_mfma_f32_32x32x16_bf16(kf, qf[sl], sB0, 0, 0, 0);
      else
        sA0 = __builtin_amdgcn_mfma_f32_32x32x16_bf16(kf, qf[sl], sA0, 0, 0, 0);
    }
    smpv2(sA0, sB0, vb, acc, lsum, hi);

    // ---- QK half 1 ----
    f32x16 sA1 = *(const f32x16*)(ldsB + t * 256 + 128 + hi * 64);
    f32x16 sB1;
#pragma unroll
    for (int r = 0; r < 16; ++r) sB1[r] = 0.0f;
#pragma unroll
    for (int sl = 0; sl < 8; ++sl) {
      const bf16x8 kf = *(const bf16x8*)(kb + (8 + sl) * 1024);
      if (sl & 1)
        sB1 = __builtin_amdgcn_mfma_f32_32x32x16_bf16(kf, qf[sl], sB1, 0, 0, 0);
      else
        sA1 = __builtin_amdgcn_mfma_f32_32x32x16_bf16(kf, qf[sl], sA1, 0, 0, 0);
    }
    smpv2(sA1, sB1, vb + 8192, acc, lsum, hi);

    __syncthreads();   // staged buf complete + all reads of cur done
  };

  // prologue: B2 chunk (4KB) + step-0 tiles
  if (wid < 4)
    gload_lds16((const char*)B2f + (size_t)(kvbase >> 5) * 128 + wid * 1024 + lane * 16,
                ldsB + wid * 1024);
  STAGE(0, 0);
  __syncthreads();

  // unrolled by 2: `cur` is a literal -> all LDS addresses fold to base+imm
  for (int t = 0; t < STEPS; t += 2) {
    BODY(0, t);
    BODY(1, t + 1);
  }

  // ---- epilogue: partner half of L, write bf16 partials ----
  lsum += __shfl_xor(lsum, 32);
  u16* op = Opart + ((size_t)ks * NQ + qrow0) * DH;
#pragma unroll
  for (int dt = 0; dt < 4; ++dt)
#pragma unroll
    for (int r = 0; r < 16; ++r) {
      const int q = (r & 3) + 8 * (r >> 2) + 4 * hi;
      op[(size_t)q * DH + dt * 32 + ln31] = f2bf(acc[dt][r]);
    }
  if (hi == 0) Lpart[(size_t)ks * NQ + qrow0 + ln31] = lsum;
}

// ---------- combine: plain sums over splits ----------
__global__ void combine(const u16* __restrict__ Opart, const float* __restrict__ Lpart,
                        const float* __restrict__ arow, float* __restrict__ out,
                        float* __restrict__ lse) {
  const int idx = blockIdx.x * 256 + threadIdx.x;
  const int row = idx >> 5;
  const int d4 = (idx & 31) * 4;
  float o0 = 0.f, o1 = 0.f, o2 = 0.f, o3 = 0.f;
  float L = 0.f;
#pragma unroll
  for (int s = 0; s < SPLITS; ++s) {
    const ushort4 v = *(const ushort4*)(Opart + ((size_t)s * NQ + row) * DH + d4);
    union { u32 u; float f; } c0, c1, c2, c3;
    c0.u = ((u32)v.x) << 16; c1.u = ((u32)v.y) << 16;
    c2.u = ((u32)v.z) << 16; c3.u = ((u32)v.w) << 16;
    o0 += c0.f; o1 += c1.f; o2 += c2.f; o3 += c3.f;
    L += Lpart[(size_t)s * NQ + row];
  }
  const float inv = 1.0f / L;
  *(float4*)(out + (size_t)row * DH + d4) =
      make_float4(o0 * inv, o1 * inv, o2 * inv, o3 * inv);
  if ((idx & 31) == 0) lse[row] = logf(L) + arow[row];
}

extern "C" void kernel_launch(void* const* d_in, const int* in_sizes, int n_in,
                              void* d_out, int out_size, void* d_ws, size_t ws_size,
                              hipStream_t stream) {
  const float* Q = (const float*)d_in[0];
  const float* K = (const float*)d_in[1];
  const float* V = (const float*)d_in[2];
  const float* h = (const float*)d_in[3];
  const float* ldq = (const float*)d_in[4];
  const float* ldk = (const float*)d_in[5];

  char* ws = (char*)d_ws;
  u16* Qa    = (u16*)(ws + 0);                       // 8192*128*2 = 2097152
  u16* Kf    = (u16*)(ws + 2097152);                 // 256*8*1024 = 2097152
  u16* Vf    = (u16*)(ws + 4194304);                 // 512*4*1024 = 2097152
  float* B2f   = (float*)(ws + 6291456);             // 8192*4 = 32768
  float* arow  = (float*)(ws + 6324224);             // 32768
  u16* Opart = (u16*)(ws + 6356992);                 // 8*8192*128*2 = 16777216
  float* Lpart = (float*)(ws + 23134208);            // 8*8192*4 = 262144 (end 23396352)

  float* out = (float*)d_out;
  float* lse = out + (size_t)NQ * DH;

  // allow >64KB dynamic LDS (config call, capture-safe — proven in r8)
  hipFuncSetAttribute(reinterpret_cast<const void*>(attn_main),
                      hipFuncAttributeMaxDynamicSharedMemorySize, LDS_BYTES);

  // fused prep: Q blocks [0,2048) | K blocks [2048,4096) | V blocks [4096,4352)
  prep_all<<<NQ / 2 + 256, 256, 0, stream>>>(Q, ldq, K, ldk, h, V, Qa, Kf, B2f, arow, Vf);
  attn_main<<<(NQ / 256) * SPLITS, 512, LDS_BYTES, stream>>>(Qa, Kf, Vf, B2f, Opart, Lpart);
  combine<<<NQ * 32 / 256, 256, 0, stream>>>(Opart, Lpart, arow, out, lse);
}

// Round 22
// 54.985 us; speedup vs baseline: 1.1261x; 1.0017x over previous
//
#include <hip/hip_runtime.h>
#include <cstddef>
#include <cstdint>

#define BETA 0.05f

typedef unsigned short u16;
typedef unsigned int u32;
typedef __attribute__((ext_vector_type(8))) short bf16x8;
typedef __attribute__((ext_vector_type(16))) float f32x16;
typedef __attribute__((ext_vector_type(4))) u32 u32x4;

constexpr int NQ = 8192;
constexpr int NK = 8192;
constexpr int DH = 128;
constexpr int SPLITS = 8;
constexpr int CHUNK = NK / SPLITS;   // 1024
constexpr int KVB = 64;
constexpr int STEPS = CHUNK / KVB;   // 16
constexpr int KSTEP = 16384;         // 16 chunks x 1024 B per step (K)
constexpr int VSTEP = 16384;         // 16 chunks x 1024 B per step (V)
constexpr int LDS_BYTES = 2 * KSTEP + 2 * VSTEP + 4096;  // 69632

// Fragment-major global layouts (chunk = 64 lanes x 16B = 1024B, one wave-load):
//  Kf chunk (tile32, sl=0..7): lane (hi,rr) holds K dims [sl*16+hi*8,+8) of kv row tile*32+rr
//  Vf chunk (b16, dt=0..3):    lane (hi,r31) holds V[kv=b16*16+hi*8..+8][d=dt*32+r31]
//  B2f[tile32][hi*16+r] f32 = b2 of kv row tile*32 + (r&3)+8*(r>>2)+4*hi  (C-layout match)

__device__ __forceinline__ u16 f2bf(float x) {
  union { float f; u32 u; } v; v.f = x;
  u32 r = (v.u + 0x7fffu + ((v.u >> 16) & 1u)) >> 16;
  return (u16)r;
}
__device__ __forceinline__ float fexp2(float x) {
#if __has_builtin(__builtin_amdgcn_exp2f)
  return __builtin_amdgcn_exp2f(x);
#else
  return exp2f(x);
#endif
}
// async global->LDS, 16B/lane; dst wave-uniform base (HW adds lane*16), src per-lane
__device__ __forceinline__ void gload_lds16(const void* gsrc, void* ldst) {
  __builtin_amdgcn_global_load_lds(
      (const __attribute__((address_space(1))) u32*)gsrc,
      (__attribute__((address_space(3))) u32*)ldst, 16, 0, 0);
}

// ---------- fused prep: Q rows | K fragment-major + b2 | V fragment-major ----------
__global__ void prep_all(const float* __restrict__ Q, const float* __restrict__ ldq,
                         const float* __restrict__ K, const float* __restrict__ ldk,
                         const float* __restrict__ h, const float* __restrict__ V,
                         u16* __restrict__ Qa, u16* __restrict__ Kf,
                         float* __restrict__ B2f, float* __restrict__ arow,
                         u16* __restrict__ Vf) {
  __shared__ float tile[64][65];
  const int bi = blockIdx.x;
  const int lane = threadIdx.x & 63;
  if (bi < NQ / 4) {
    const int row = bi * 4 + (threadIdx.x >> 6);
    const float2 q2 = *(const float2*)(Q + (size_t)row * DH + lane * 2);
    float sq = q2.x * q2.x + q2.y * q2.y;
#pragma unroll
    for (int off = 32; off > 0; off >>= 1) sq += __shfl_xor(sq, off);
    const float SC = 2.0f * BETA * 1.4426950408889634f;  // fold 2*beta*log2e
    ushort2 o; o.x = f2bf(SC * q2.x); o.y = f2bf(SC * q2.y);
    *(ushort2*)(Qa + (size_t)row * DH + lane * 2) = o;
    if (lane == 0) arow[row] = -BETA * sq - ldq[row] + logf(h[row]);
  } else if (bi < NQ / 2) {
    const int row = (bi - NQ / 4) * 4 + (threadIdx.x >> 6);
    const float2 k2 = *(const float2*)(K + (size_t)row * DH + lane * 2);
    float sq = k2.x * k2.x + k2.y * k2.y;
#pragma unroll
    for (int off = 32; off > 0; off >>= 1) sq += __shfl_xor(sq, off);
    ushort2 o; o.x = f2bf(k2.x); o.y = f2bf(k2.y);
    char* dst = (char*)Kf + ((size_t)(row >> 5) * 8 + (lane >> 3)) * 1024
              + ((((lane >> 2) & 1) * 32) + (row & 31)) * 16 + (lane & 3) * 4;
    *(ushort2*)dst = o;
    if (lane == 0) {
      const float b2 = (-BETA * sq - ldk[row] - logf(h[row])) * 1.4426950408889634f;
      const int w = row & 31;
      B2f[(size_t)(row >> 5) * 32 + ((w >> 2) & 1) * 16 + (w & 3) + 4 * (w >> 3)] = b2;
    }
  } else {
    // V transpose blocks: vb = bi - NQ/2 in [0, 256); j0 = (vb>>1)*64, d0 = (vb&1)*64
    const int vb = bi - NQ / 2;
    const int j0 = (vb >> 1) * 64;
    const int d0 = (vb & 1) * 64;
    const int t = threadIdx.x;        // 256
    const int r = t >> 4;
    const int c = (t & 15) * 4;
#pragma unroll
    for (int rr = r; rr < 64; rr += 16) {
      const float4 v = *(const float4*)(V + (size_t)(j0 + rr) * DH + d0 + c);
      tile[rr][c + 0] = v.x; tile[rr][c + 1] = v.y;
      tile[rr][c + 2] = v.z; tile[rr][c + 3] = v.w;
    }
    __syncthreads();
    const int kv8i = t & 7;
    const int dl0 = t >> 3;           // 0..31
#pragma unroll
    for (int dd = dl0; dd < 64; dd += 32) {
      const int dg = d0 + dd;
      const int b16g = (j0 >> 4) + (kv8i >> 1);
      const int hi = kv8i & 1;
      union { u32x4 q; u16 s[8]; } pk;
#pragma unroll
      for (int m = 0; m < 8; ++m) pk.s[m] = f2bf(tile[kv8i * 8 + m][dd]);
      *(u32x4*)((char*)Vf + ((size_t)(b16g * 4 + (dg >> 5)) * 1024)
                + ((hi * 32) + (dg & 31)) * 16) = pk.q;
    }
  }
}

// softmax + PV for one 32-kv half; dual-chain s = sA + sB; V reads fused into PV
__device__ __forceinline__ void smpv2(const f32x16& sA, const f32x16& sB,
                                      const char* vbh,
                                      f32x16 acc[4], float& lsum, int hi) {
  float p[16];
#pragma unroll
  for (int r = 0; r < 16; ++r) p[r] = fexp2(sA[r] + sB[r]);
  {
    float t0 = (p[0] + p[1]) + (p[2] + p[3]);
    float t1 = (p[4] + p[5]) + (p[6] + p[7]);
    float t2 = (p[8] + p[9]) + (p[10] + p[11]);
    float t3 = (p[12] + p[13]) + (p[14] + p[15]);
    lsum += (t0 + t1) + (t2 + t3);
  }
  u32 pk0, pk1, pk2, pk3, pk4, pk5, pk6, pk7;
  asm("v_cvt_pk_bf16_f32 %0, %1, %2" : "=v"(pk0) : "v"(p[0]),  "v"(p[1]));
  asm("v_cvt_pk_bf16_f32 %0, %1, %2" : "=v"(pk1) : "v"(p[2]),  "v"(p[3]));
  asm("v_cvt_pk_bf16_f32 %0, %1, %2" : "=v"(pk2) : "v"(p[4]),  "v"(p[5]));
  asm("v_cvt_pk_bf16_f32 %0, %1, %2" : "=v"(pk3) : "v"(p[6]),  "v"(p[7]));
  asm("v_cvt_pk_bf16_f32 %0, %1, %2" : "=v"(pk4) : "v"(p[8]),  "v"(p[9]));
  asm("v_cvt_pk_bf16_f32 %0, %1, %2" : "=v"(pk5) : "v"(p[10]), "v"(p[11]));
  asm("v_cvt_pk_bf16_f32 %0, %1, %2" : "=v"(pk6) : "v"(p[12]), "v"(p[13]));
  asm("v_cvt_pk_bf16_f32 %0, %1, %2" : "=v"(pk7) : "v"(p[14]), "v"(p[15]));
  const bool hb = (hi != 0);
#pragma unroll
  for (int ksl = 0; ksl < 2; ++ksl) {
    const u32 a0 = ksl ? pk4 : pk0, a1 = ksl ? pk5 : pk1;
    const u32 b0 = ksl ? pk6 : pk2, b1 = ksl ? pk7 : pk3;
    const u32 own0 = hb ? b0 : a0, own1 = hb ? b1 : a1;
    const u32 snd0 = hb ? a0 : b0, snd1 = hb ? a1 : b1;
    const u32 rcv0 = (u32)__shfl_xor((int)snd0, 32);
    const u32 rcv1 = (u32)__shfl_xor((int)snd1, 32);
    union { u32x4 u; bf16x8 b; } pa;
    pa.u[0] = hb ? rcv0 : own0;
    pa.u[1] = hb ? rcv1 : own1;
    pa.u[2] = hb ? own0 : rcv0;
    pa.u[3] = hb ? own1 : rcv1;
#pragma unroll
    for (int dt = 0; dt < 4; ++dt) {
      const bf16x8 vf = *(const bf16x8*)(vbh + (ksl * 4 + dt) * 1024);
      acc[dt] = __builtin_amdgcn_mfma_f32_32x32x16_bf16(pa.b, vf, acc[dt], 0, 0, 0);
    }
  }
}

// ---------- main: fragment-major + LDS distribution (r18 config, best) ----------
__global__ __launch_bounds__(512) void attn_main(
    const u16* __restrict__ Qa, const u16* __restrict__ Kf,
    const u16* __restrict__ Vf, const float* __restrict__ B2f,
    u16* __restrict__ Opart, float* __restrict__ Lpart) {
  extern __shared__ __align__(16) char lds[];    // 69632 B dynamic
  char* ldsK = lds;                              // [2][16384]
  char* ldsV = lds + 2 * KSTEP;                  // [2][16384]
  char* ldsB = lds + 2 * KSTEP + 2 * VSTEP;      // [4096]

  const int tid = threadIdx.x;
  const int wid = tid >> 6;
  const int lane = tid & 63;
  const int hi = lane >> 5;
  const int ln31 = lane & 31;
  const int bi = blockIdx.x;
  const int ks = bi & 7;          // split id -> XCD (L2 chunk locality)
  const int qg = bi >> 3;
  const int kvbase = ks * CHUNK;
  const int qrow0 = qg * 256 + wid * 32;

  // Q fragments (B-operand): col q = ln31, dims sl*16 + hi*8 + j
  bf16x8 qf[8];
#pragma unroll
  for (int sl = 0; sl < 8; ++sl)
    qf[sl] = *(const bf16x8*)((const char*)Qa + (size_t)(qrow0 + ln31) * 256 + sl * 32 + hi * 16);

  f32x16 acc[4];
#pragma unroll
  for (int dt = 0; dt < 4; ++dt)
#pragma unroll
    for (int r = 0; r < 16; ++r) acc[dt][r] = 0.0f;
  float lsum = 0.0f;

  const char* KfG = (const char*)Kf + ((size_t)(kvbase >> 5) * 8) * 1024 + lane * 16;
  const char* VfG = (const char*)Vf + ((size_t)(kvbase >> 4) * 4) * 1024 + lane * 16;

  // stage: wave w moves K chunks {2w,2w+1} + V chunks {2w,2w+1} of step into buf
  auto STAGE = [&](int buf, int step) {
    const char* ksrc = KfG + (size_t)step * KSTEP + wid * 2048;
    const char* vsrc = VfG + (size_t)step * VSTEP + wid * 2048;
    char* kdst = ldsK + buf * KSTEP + wid * 2048;
    char* vdst = ldsV + buf * VSTEP + wid * 2048;
    gload_lds16(ksrc, kdst);
    gload_lds16(ksrc + 1024, kdst + 1024);
    gload_lds16(vsrc, vdst);
    gload_lds16(vsrc + 1024, vdst + 1024);
  };

  // one full step on compile-time buffer index `cur`
  auto BODY = [&](int cur, int t) {
    if (t < STEPS - 1) STAGE(cur ^ 1, t + 1);   // drains at end-of-step barrier

    const char* kb = ldsK + cur * KSTEP + lane * 16;
    const char* vb = ldsV + cur * VSTEP + lane * 16;

    // ---- QK half 0: dual chains (even->A with b2-init, odd->B), fused reads ----
    f32x16 sA0 = *(const f32x16*)(ldsB + t * 256 + hi * 64);
    f32x16 sB0;
#pragma unroll
    for (int r = 0; r < 16; ++r) sB0[r] = 0.0f;
#pragma unroll
    for (int sl = 0; sl < 8; ++sl) {
      const bf16x8 kf = *(const bf16x8*)(kb + sl * 1024);
      if (sl & 1)
        sB0 = __builtin_amdgcn_mfma_f32_32x32x16_bf16(kf, qf[sl], sB0, 0, 0, 0);
      else
        sA0 = __builtin_amdgcn_mfma_f32_32x32x16_bf16(kf, qf[sl], sA0, 0, 0, 0);
    }
    smpv2(sA0, sB0, vb, acc, lsum, hi);

    // ---- QK half 1 ----
    f32x16 sA1 = *(const f32x16*)(ldsB + t * 256 + 128 + hi * 64);
    f32x16 sB1;
#pragma unroll
    for (int r = 0; r < 16; ++r) sB1[r] = 0.0f;
#pragma unroll
    for (int sl = 0; sl < 8; ++sl) {
      const bf16x8 kf = *(const bf16x8*)(kb + (8 + sl) * 1024);
      if (sl & 1)
        sB1 = __builtin_amdgcn_mfma_f32_32x32x16_bf16(kf, qf[sl], sB1, 0, 0, 0);
      else
        sA1 = __builtin_amdgcn_mfma_f32_32x32x16_bf16(kf, qf[sl], sA1, 0, 0, 0);
    }
    smpv2(sA1, sB1, vb + 8192, acc, lsum, hi);

    __syncthreads();   // staged buf complete + all reads of cur done
  };

  // prologue: B2 chunk (4KB) + step-0 tiles
  if (wid < 4)
    gload_lds16((const char*)B2f + (size_t)(kvbase >> 5) * 128 + wid * 1024 + lane * 16,
                ldsB + wid * 1024);
  STAGE(0, 0);
  __syncthreads();

  // unrolled by 2: `cur` is a literal -> all LDS addresses fold to base+imm
  for (int t = 0; t < STEPS; t += 2) {
    BODY(0, t);
    BODY(1, t + 1);
  }

  // ---- epilogue: partner half of L, write bf16 partials ----
  lsum += __shfl_xor(lsum, 32);
  u16* op = Opart + ((size_t)ks * NQ + qrow0) * DH;
#pragma unroll
  for (int dt = 0; dt < 4; ++dt)
#pragma unroll
    for (int r = 0; r < 16; ++r) {
      const int q = (r & 3) + 8 * (r >> 2) + 4 * hi;
      op[(size_t)q * DH + dt * 32 + ln31] = f2bf(acc[dt][r]);
    }
  if (hi == 0) Lpart[(size_t)ks * NQ + qrow0 + ln31] = lsum;
}

// ---------- combine: plain sums over splits ----------
__global__ void combine(const u16* __restrict__ Opart, const float* __restrict__ Lpart,
                        const float* __restrict__ arow, float* __restrict__ out,
                        float* __restrict__ lse) {
  const int idx = blockIdx.x * 256 + threadIdx.x;
  const int row = idx >> 5;
  const int d4 = (idx & 31) * 4;
  float o0 = 0.f, o1 = 0.f, o2 = 0.f, o3 = 0.f;
  float L = 0.f;
#pragma unroll
  for (int s = 0; s < SPLITS; ++s) {
    const ushort4 v = *(const ushort4*)(Opart + ((size_t)s * NQ + row) * DH + d4);
    union { u32 u; float f; } c0, c1, c2, c3;
    c0.u = ((u32)v.x) << 16; c1.u = ((u32)v.y) << 16;
    c2.u = ((u32)v.z) << 16; c3.u = ((u32)v.w) << 16;
    o0 += c0.f; o1 += c1.f; o2 += c2.f; o3 += c3.f;
    L += Lpart[(size_t)s * NQ + row];
  }
  const float inv = 1.0f / L;
  *(float4*)(out + (size_t)row * DH + d4) =
      make_float4(o0 * inv, o1 * inv, o2 * inv, o3 * inv);
  if ((idx & 31) == 0) lse[row] = logf(L) + arow[row];
}

extern "C" void kernel_launch(void* const* d_in, const int* in_sizes, int n_in,
                              void* d_out, int out_size, void* d_ws, size_t ws_size,
                              hipStream_t stream) {
  const float* Q = (const float*)d_in[0];
  const float* K = (const float*)d_in[1];
  const float* V = (const float*)d_in[2];
  const float* h = (const float*)d_in[3];
  const float* ldq = (const float*)d_in[4];
  const float* ldk = (const float*)d_in[5];

  char* ws = (char*)d_ws;
  u16* Qa    = (u16*)(ws + 0);                       // 8192*128*2 = 2097152
  u16* Kf    = (u16*)(ws + 2097152);                 // 256*8*1024 = 2097152
  u16* Vf    = (u16*)(ws + 4194304);                 // 512*4*1024 = 2097152
  float* B2f   = (float*)(ws + 6291456);             // 8192*4 = 32768
  float* arow  = (float*)(ws + 6324224);             // 32768
  u16* Opart = (u16*)(ws + 6356992);                 // 8*8192*128*2 = 16777216
  float* Lpart = (float*)(ws + 23134208);            // 8*8192*4 = 262144 (end 23396352)

  float* out = (float*)d_out;
  float* lse = out + (size_t)NQ * DH;

  // allow >64KB dynamic LDS (config call, capture-safe — proven in r8)
  hipFuncSetAttribute(reinterpret_cast<const void*>(attn_main),
                      hipFuncAttributeMaxDynamicSharedMemorySize, LDS_BYTES);

  // fused prep: Q blocks [0,2048) | K blocks [2048,4096) | V blocks [4096,4352)
  prep_all<<<NQ / 2 + 256, 256, 0, stream>>>(Q, ldq, K, ldk, h, V, Qa, Kf, B2f, arow, Vf);
  attn_main<<<(NQ / 256) * SPLITS, 512, LDS_BYTES, stream>>>(Qa, Kf, Vf, B2f, Opart, Lpart);
  combine<<<NQ * 32 / 256, 256, 0, stream>>>(Opart, Lpart, arow, out, lse);
}